// Round 14
// baseline (3691.592 us; speedup 1.0000x reference)
//
#include <hip/hip_runtime.h>
#include <hip/hip_bf16.h>
#include <cstdint>
#include <cstddef>

#define D_DIM 2048
#define L_SEQ 2048
#define B_SZ 4
#define M_ROWS (B_SZ * L_SEQ)   /* 8192 */
#define NT_COLS (3 * D_DIM)     /* 6144: seg0=A, seg1=dt, seg2=rawB */
#define NCH 16
#define CHUNK (L_SEQ / NCH)     /* 128 */

typedef __bf16 bf16_t;
typedef bf16_t bf16x8 __attribute__((ext_vector_type(8)));
typedef float f32x4 __attribute__((ext_vector_type(4)));

__device__ __forceinline__ void gl_lds16(const void* g, void* l) {
    __builtin_amdgcn_global_load_lds(
        (const __attribute__((address_space(1))) unsigned int*)g,
        (__attribute__((address_space(3))) unsigned int*)l, 16, 0, 0);
}

#define BARR()   __builtin_amdgcn_s_barrier()
#define LGKM0()  { asm volatile("s_waitcnt lgkmcnt(0)" ::: "memory"); \
                   __builtin_amdgcn_sched_barrier(0); }
#define VMC6()   asm volatile("s_waitcnt vmcnt(6)" ::: "memory")
#define VMC0()   asm volatile("s_waitcnt vmcnt(0)" ::: "memory")

// ---------------- convert force f32 -> bf16 (16B stores) ----------------
__global__ __launch_bounds__(256) void cvt_bf16_kernel(
    const float* __restrict__ in, bf16_t* __restrict__ out, int n8)
{
    int i = blockIdx.x * 256 + threadIdx.x;
    if (i >= n8) return;
    float4 f0 = ((const float4*)in)[2 * i];
    float4 f1 = ((const float4*)in)[2 * i + 1];
    bf16x8 o;
    o[0] = (bf16_t)f0.x; o[1] = (bf16_t)f0.y; o[2] = (bf16_t)f0.z; o[3] = (bf16_t)f0.w;
    o[4] = (bf16_t)f1.x; o[5] = (bf16_t)f1.y; o[6] = (bf16_t)f1.z; o[7] = (bf16_t)f1.w;
    ((bf16x8*)out)[i] = o;
}

// ------- transpose W[k][j] -> Wt[j][k] with f32->bf16; z picks matrix -------
__global__ __launch_bounds__(256) void transpose_w_kernel(
    const float* __restrict__ W0, const float* __restrict__ W1,
    const float* __restrict__ W2, bf16_t* __restrict__ Wt)
{
    __shared__ float tile[32][33];
    const float* W = (blockIdx.z == 0) ? W0 : (blockIdx.z == 1) ? W1 : W2;
    bf16_t* dst = Wt + (size_t)blockIdx.z * D_DIM * D_DIM;
    int j0 = blockIdx.x * 32, k0 = blockIdx.y * 32;
    int tx = threadIdx.x, ty = threadIdx.y;      // block (32, 8)
#pragma unroll
    for (int i = 0; i < 4; i++) {
        int k = k0 + ty + i * 8;
        tile[ty + i * 8][tx] = W[(size_t)k * D_DIM + j0 + tx];
    }
    __syncthreads();
#pragma unroll
    for (int i = 0; i < 4; i++) {
        int j = j0 + ty + i * 8;
        dst[(size_t)j * D_DIM + k0 + tx] = (bf16_t)tile[tx][ty + i * 8];
    }
}

// ---------------- fused bf16 GEMM: [8192 x 2048] @ [2048 x 6144] ----------------
// 8-phase counted-vmcnt template (T3+T4, m201-style), derived with per-region
// hazard proofs. 256x256 tile, BK=64, 8 waves (2M x 4N), wave owns 128x64.
// LDS 128KB = [2 dbuf][A,B][2 K-halves of 256rows x 32cols = 16KB].
// Per K-tile: 4 phases x 16 MFMA. Phase = {ds-reads, stage ONE K-half,
// barrier, lgkmcnt(0)+sched_barrier (rule 18), setprio, MFMA, setprio,
// [vmcnt(6) at P4], barrier}. Stage lag pattern (region retired one phase
// before its stage): P1: B-kh1(t+1)->dbuf[t+1], P2: A-kh0(t+2)->dbuf[t],
// P3: B-kh0(t+2), P4: A-kh1(t+2). vmcnt(6) keeps 3 halves in flight.
// Rationale: 2-phase family plateaued at ~650 TF across R8/R12/R13
// (MfmaUtil pinned ~28 regardless of occupancy/LDS-traffic) = m233's
// measured stage+vmcnt(0)+barrier wall; counted vmcnt amortizes it.
// Swizzle = R4/R13-verified 0-conflict pair (BK=32-format rows of 64B):
//   stage: LDS dest linear, global 16B-slot ^= ((row>>1)&3)
//   read : slot = (lane>>4) ^ ((frow>>1)&3)
// NOTE (R5): epilogue stores stay f32. (R9): 16x16x32 MFMA only.
#define STAGE_H(REG, G0, G1, KOFS) {                                           \
    gl_lds16((G0) + (size_t)(KOFS), (REG) + w * 512);                          \
    gl_lds16((G1) + (size_t)(KOFS), (REG) + 4096 + w * 512);                   \
}

#define MFMA8(N0, N1, B0, B1)                                                  \
    __builtin_amdgcn_s_setprio(1);                                             \
    _Pragma("unroll") for (int m = 0; m < 8; m++) {                            \
        acc[m][N0] = __builtin_amdgcn_mfma_f32_16x16x32_bf16(af[m], B0, acc[m][N0], 0, 0, 0); \
        acc[m][N1] = __builtin_amdgcn_mfma_f32_16x16x32_bf16(af[m], B1, acc[m][N1], 0, 0, 0); \
    }                                                                          \
    __builtin_amdgcn_s_setprio(0);

#define TILE(T, AK0, AK1, BH0, BH1, SA0, SA1, SB0, SNB1, DO1, DO2, VM) {       \
    /* P1: A ks0 (8 rd) + B n01 ks0 (2 rd) | stage B-kh1(T+1) */               \
    _Pragma("unroll") for (int m = 0; m < 8; m++)                              \
        af[m] = *(const bf16x8*)&(AK0)[lofA + m * 512];                        \
    bf0 = *(const bf16x8*)&(BH0)[lofB];                                        \
    bf1 = *(const bf16x8*)&(BH0)[lofB + 512];                                  \
    if (DO1) STAGE_H(SNB1, gB0, gB1, ((T) + 1) * 64 + 32);                     \
    BARR(); LGKM0();                                                           \
    MFMA8(0, 1, bf0, bf1);                                                     \
    BARR();                                                                    \
    /* P2: B n23 ks0 (2 rd) | stage A-kh0(T+2) */                              \
    bf0 = *(const bf16x8*)&(BH0)[lofB + 1024];                                 \
    bf1 = *(const bf16x8*)&(BH0)[lofB + 1536];                                 \
    if (DO2) STAGE_H(SA0, gA0, gA1, ((T) + 2) * 64);                           \
    BARR(); LGKM0();                                                           \
    MFMA8(2, 3, bf0, bf1);                                                     \
    BARR();                                                                    \
    /* P3: A ks1 (8 rd) + B n01 ks1 (2 rd) | stage B-kh0(T+2) */               \
    _Pragma("unroll") for (int m = 0; m < 8; m++)                              \
        af[m] = *(const bf16x8*)&(AK1)[lofA + m * 512];                        \
    bf0 = *(const bf16x8*)&(BH1)[lofB];                                        \
    bf1 = *(const bf16x8*)&(BH1)[lofB + 512];                                  \
    if (DO2) STAGE_H(SB0, gB0, gB1, ((T) + 2) * 64);                           \
    BARR(); LGKM0();                                                           \
    MFMA8(0, 1, bf0, bf1);                                                     \
    BARR();                                                                    \
    /* P4: B n23 ks1 (2 rd) | stage A-kh1(T+2) | VM */                         \
    bf0 = *(const bf16x8*)&(BH1)[lofB + 1024];                                 \
    bf1 = *(const bf16x8*)&(BH1)[lofB + 1536];                                 \
    if (DO2) STAGE_H(SA1, gA0, gA1, ((T) + 2) * 64 + 32);                      \
    BARR(); LGKM0();                                                           \
    MFMA8(2, 3, bf0, bf1);                                                     \
    VM;                                                                        \
    BARR();                                                                    \
}

__global__ __launch_bounds__(512) void gemm_fused_kernel(
    const bf16_t* __restrict__ Abf,   // force bf16 [8192][2048]
    const bf16_t* __restrict__ Wt,    // [6144][2048] (W^T, concat A|dt|B)
    const float* __restrict__ bA, const float* __restrict__ bdt,
    const float* __restrict__ bB, const float* __restrict__ scales,
    float* __restrict__ outA,         // -> d_out x-region (staging)
    float* __restrict__ outDT,        // -> ws
    float* __restrict__ outB)         // -> d_out v-region (staging)
{
    // [dbuf][A,B][K-half]: 8 regions x 16 KB (256 rows x 32 cols bf16)
    __shared__ bf16_t a0k0[256 * 32], a0k1[256 * 32];
    __shared__ bf16_t b0k0[256 * 32], b0k1[256 * 32];
    __shared__ bf16_t a1k0[256 * 32], a1k1[256 * 32];
    __shared__ bf16_t b1k0[256 * 32], b1k1[256 * 32];

    const int bm0 = blockIdx.x * 256;         // M block (fastest)
    const int bn0 = blockIdx.y * 256;         // NT block
    const int t = threadIdx.x;                // 0..511
    const int lane = t & 63, w = t >> 6;      // 8 waves
    const int wr = (w >> 2) * 128;            // 2 m-groups (wave: 128 rows)
    const int wc = (w & 3) * 64;              // 4 n-groups (wave: 64 cols)

    f32x4 acc[8][4] = {};
    bf16x8 af[8], bf0, bf1;

    // staging: thread t covers (row t>>2, 16B-slot t&3) and (+128 rows);
    // global col pre-swizzled slot ^ ((row>>1)&3) = (t&3) ^ ((t>>3)&3)
    const int srow = t >> 2;
    const int scol = (((t & 3) ^ ((t >> 3) & 3)) << 3);   // elements
    const bf16_t* gA0 = Abf + (size_t)(bm0 + srow) * D_DIM + scol;
    const bf16_t* gA1 = Abf + (size_t)(bm0 + 128 + srow) * D_DIM + scol;
    const bf16_t* gB0 = Wt + (size_t)(bn0 + srow) * D_DIM + scol;
    const bf16_t* gB1 = Wt + (size_t)(bn0 + 128 + srow) * D_DIM + scol;

    // frag reads (R4/R13-verified 0-conflict): row = frow in 16-row group
    const int frow = lane & 15;
    const int q = lane >> 4;
    const int swz = ((q ^ ((frow >> 1) & 3)) << 3);       // elements
    const int lofA = (wr + frow) * 32 + swz;              // + m*512
    const int lofB = (wc + frow) * 32 + swz;              // + n*512

    // prologue: tile0 all 4 halves + tile1 {A-kh0, B-kh0, A-kh1};
    // vmcnt(6) -> tile0 landed, 3 halves of tile1 in flight (steady state)
    STAGE_H(a0k0, gA0, gA1, 0);
    STAGE_H(b0k0, gB0, gB1, 0);
    STAGE_H(a0k1, gA0, gA1, 32);
    STAGE_H(b0k1, gB0, gB1, 32);
    STAGE_H(a1k0, gA0, gA1, 64);
    STAGE_H(b1k0, gB0, gB1, 64);
    STAGE_H(a1k1, gA0, gA1, 96);
    VMC6();
    BARR();

    // main loop: 15 iters x 2 tiles (t = 0..29), fully steady
#pragma unroll 1
    for (int i = 0; i < 15; ++i) {
        const int T0 = 2 * i;
        TILE(T0,     a0k0, a0k1, b0k0, b0k1, a0k0, a0k1, b0k0, b1k1, 1, 1, VMC6());
        TILE(T0 + 1, a1k0, a1k1, b1k0, b1k1, a1k0, a1k1, b1k0, b0k1, 1, 1, VMC6());
    }
    // tail: t=30 stages only B-kh1(31); drain; t=31 no stages
    TILE(30, a0k0, a0k1, b0k0, b0k1, a0k0, a0k1, b0k0, b1k1, 1, 0, VMC0());
    TILE(31, a1k0, a1k1, b1k0, b1k1, a1k0, a1k1, b1k0, b0k1, 0, 0, ((void)0));

    // epilogue: C/D layout col = lane&15, row = (lane>>4)*4 + reg  [m89-verified]
    const int seg = bn0 >> 11;                        // 0=A, 1=dt, 2=rawB
    const int dbase = (bn0 & 2047) + wc + (lane & 15);
    const int rowbase = bm0 + wr + (q << 2);

    if (seg == 0) {
        float bias[4];
#pragma unroll
        for (int n = 0; n < 4; n++) bias[n] = bA[dbase + n * 16];
#pragma unroll
        for (int m = 0; m < 8; m++)
#pragma unroll
            for (int n = 0; n < 4; n++)
#pragma unroll
                for (int r = 0; r < 4; r++) {
                    size_t idx = (size_t)(rowbase + m * 16 + r) * D_DIM + dbase + n * 16;
                    outA[idx] = 1.0f / (1.0f + __expf(-(acc[m][n][r] + bias[n])));
                }
    } else if (seg == 1) {
        float bias[4], sc[4];
#pragma unroll
        for (int n = 0; n < 4; n++) { bias[n] = bdt[dbase + n * 16]; sc[n] = scales[dbase + n * 16]; }
#pragma unroll
        for (int m = 0; m < 8; m++)
#pragma unroll
            for (int n = 0; n < 4; n++)
#pragma unroll
                for (int r = 0; r < 4; r++) {
                    size_t idx = (size_t)(rowbase + m * 16 + r) * D_DIM + dbase + n * 16;
                    float xx = acc[m][n][r] + bias[n];
                    float sp = xx > 0.f ? xx + log1pf(__expf(-xx)) : log1pf(__expf(xx));
                    outDT[idx] = sp * 0.1f * sc[n];
                }
    } else {
        float bias[4];
#pragma unroll
        for (int n = 0; n < 4; n++) bias[n] = bB[dbase + n * 16];
#pragma unroll
        for (int m = 0; m < 8; m++)
#pragma unroll
            for (int n = 0; n < 4; n++)
#pragma unroll
                for (int r = 0; r < 4; r++) {
                    size_t idx = (size_t)(rowbase + m * 16 + r) * D_DIM + dbase + n * 16;
                    outB[idx] = acc[m][n][r] + bias[n];
                }
    }
}

// ---------------- scan pass 1: per-chunk affine aggregates ----------------
// step map: v' = a v + bv ; x' = x + dt v'  =>  (P,R,U,W):
//   v_out = P v + U ; x_out = R v + x + W
// 2 adjacent d-channels per thread (float2 loads).
__global__ __launch_bounds__(256) void scan_pass1_kernel(
    const float* __restrict__ Aarr, const float* __restrict__ Braw,
    const float* __restrict__ dtv, float4* __restrict__ agg)
{
    int pp = blockIdx.x * 256 + threadIdx.x;    // 65536 pair-threads
    int dp = (pp & 1023) << 1;                  // d pair base
    int c = (pp >> 10) & (NCH - 1);
    int b = pp >> 14;
    size_t base = ((size_t)(b * L_SEQ + c * CHUNK)) * D_DIM + dp;
    float P0 = 1.f, R0 = 0.f, U0 = 0.f, W0 = 0.f;
    float P1 = 1.f, R1 = 0.f, U1 = 0.f, W1 = 0.f;
#pragma unroll 4
    for (int tt = 0; tt < CHUNK; tt++) {
        size_t idx = base + (size_t)tt * D_DIM;
        float2 a2  = *(const float2*)&Aarr[idx];
        float2 rb2 = *(const float2*)&Braw[idx];
        float2 dt2 = *(const float2*)&dtv[idx];
        float bv0 = rb2.x * dt2.x, bv1 = rb2.y * dt2.y;
        float da0 = dt2.x * a2.x,  da1 = dt2.y * a2.y;
        R0 = da0 * P0 + R0;  W0 = da0 * U0 + dt2.x * bv0 + W0;
        U0 = a2.x * U0 + bv0;  P0 = a2.x * P0;
        R1 = da1 * P1 + R1;  W1 = da1 * U1 + dt2.y * bv1 + W1;
        U1 = a2.y * U1 + bv1;  P1 = a2.y * P1;
    }
    int ch = ((b * NCH + c) << 11) + dp;
    agg[ch]     = make_float4(P0, R0, U0, W0);
    agg[ch + 1] = make_float4(P1, R1, U1, W1);
}

// ---------------- scan pass 2: combine chunk aggregates ----------------
__global__ __launch_bounds__(256) void scan_pass2_kernel(
    const float4* __restrict__ agg, float2* __restrict__ pre)
{
    int tid = blockIdx.x * 256 + threadIdx.x;   // 8192 channels
    int d = tid & (D_DIM - 1);
    int b = tid >> 11;
    float v = 0.f, x = 0.f;
#pragma unroll
    for (int c = 0; c < NCH; c++) {
        int i = ((b * NCH + c) << 11) + d;
        float4 g = agg[i];
        pre[i] = make_float2(v, x);             // state entering chunk c
        float vn = g.x * v + g.z;
        x = g.y * v + x + g.w;                  // uses old v
        v = vn;
    }
}

// ---------------- scan pass 3: replay chunk, write outputs in place ----------------
// A staged in xout, rawB staged in vout; overwritten in place
// (read-before-write, same element, same thread).
__global__ __launch_bounds__(256) void scan_pass3_kernel(
    const float* __restrict__ dtv, const float2* __restrict__ pre,
    float* __restrict__ xout, float* __restrict__ vout)
{
    int pp = blockIdx.x * 256 + threadIdx.x;    // 65536 pair-threads
    int dp = (pp & 1023) << 1;
    int c = (pp >> 10) & (NCH - 1);
    int b = pp >> 14;
    int ch = ((b * NCH + c) << 11) + dp;
    float4 pv = *(const float4*)&pre[ch];       // {v0,x0,v1,x1}
    float v0 = pv.x, x0 = pv.y, v1 = pv.z, x1 = pv.w;
    size_t base = ((size_t)(b * L_SEQ + c * CHUNK)) * D_DIM + dp;
#pragma unroll 4
    for (int tt = 0; tt < CHUNK; tt++) {
        size_t idx = base + (size_t)tt * D_DIM;
        float2 a2  = *(const float2*)&xout[idx];   // A (staged)
        float2 rb2 = *(const float2*)&vout[idx];   // rawB (staged)
        float2 dt2 = *(const float2*)&dtv[idx];
        v0 = a2.x * v0 + rb2.x * dt2.x;
        x0 = x0 + v0 * dt2.x;
        v1 = a2.y * v1 + rb2.y * dt2.y;
        x1 = x1 + v1 * dt2.y;
        *(float2*)&vout[idx] = make_float2(v0, v1);
        *(float2*)&xout[idx] = make_float2(x0, x1);
    }
}

extern "C" void kernel_launch(void* const* d_in, const int* in_sizes, int n_in,
                              void* d_out, int out_size, void* d_ws, size_t ws_size,
                              hipStream_t stream) {
    // inputs: 0:x 1:v 2:force 3:WA 4:bA 5:WB 6:bB 7:Wdt 8:bdt 9:scales
    const float* force  = (const float*)d_in[2];
    const float* WA     = (const float*)d_in[3];
    const float* bA     = (const float*)d_in[4];
    const float* WB     = (const float*)d_in[5];
    const float* bB     = (const float*)d_in[6];
    const float* Wdt    = (const float*)d_in[7];
    const float* bdt    = (const float*)d_in[8];
    const float* scales = (const float*)d_in[9];

    float* xout = (float*)d_out;                          // x_seq [8192*2048]
    float* vout = xout + (size_t)M_ROWS * D_DIM;          // v_seq

    // ws layout (123 MiB): R1 layout
    char* ws = (char*)d_ws;
    bf16_t* fbf = (bf16_t*)ws;                                     // 32 MB
    bf16_t* wt  = (bf16_t*)(ws + (size_t)33554432);                // 24 MB
    float*  dtv = (float*)(ws + (size_t)33554432 + 25165824);      // 64 MB
    float4* agg = (float4*)(ws + (size_t)33554432 + 25165824 + 67108864); // 2 MB
    float2* pre = (float2*)(ws + (size_t)33554432 + 25165824 + 67108864 + 2097152); // 1 MB

    // 1) force -> bf16
    {
        int n8 = M_ROWS * D_DIM / 8;
        cvt_bf16_kernel<<<n8 / 256, 256, 0, stream>>>(force, fbf, n8);
    }
    // 2) transpose + convert weights into concat [6144][2048]: A | dt | B
    {
        dim3 grid(D_DIM / 32, D_DIM / 32, 3), block(32, 8);
        transpose_w_kernel<<<grid, block, 0, stream>>>(WA, Wdt, WB, wt);
    }
    // 3) fused GEMM + activations (256^2 tile, BK=64, 8-phase counted vmcnt)
    {
        dim3 grid(M_ROWS / 256, NT_COLS / 256);   // (32, 24)
        gemm_fused_kernel<<<grid, 512, 0, stream>>>(fbf, wt, bA, bdt, bB, scales,
                                                    xout, dtv, vout);
    }
    // 4-6) chunked associative scan (2 channels per thread)
    scan_pass1_kernel<<<(B_SZ * NCH * D_DIM / 2) / 256, 256, 0, stream>>>(xout, vout, dtv, agg);
    scan_pass2_kernel<<<(B_SZ * D_DIM) / 256, 256, 0, stream>>>(agg, pre);
    scan_pass3_kernel<<<(B_SZ * NCH * D_DIM / 2) / 256, 256, 0, stream>>>(dtv, pre, xout, vout);
}

// Round 15
// 407.462 us; speedup vs baseline: 9.0600x; 9.0600x over previous
//
#include <hip/hip_runtime.h>
#include <hip/hip_bf16.h>
#include <cstdint>
#include <cstddef>

#define D_DIM 2048
#define L_SEQ 2048
#define B_SZ 4
#define M_ROWS (B_SZ * L_SEQ)   /* 8192 */
#define NT_COLS (3 * D_DIM)     /* 6144: seg0=A, seg1=dt, seg2=rawB */
#define NCH 16
#define CHUNK (L_SEQ / NCH)     /* 128 */

typedef __bf16 bf16_t;
typedef bf16_t bf16x8 __attribute__((ext_vector_type(8)));
typedef float f32x4 __attribute__((ext_vector_type(4)));

__device__ __forceinline__ void gl_lds16(const void* g, void* l) {
    __builtin_amdgcn_global_load_lds(
        (const __attribute__((address_space(1))) unsigned int*)g,
        (__attribute__((address_space(3))) unsigned int*)l, 16, 0, 0);
}

#define BAR()    asm volatile("s_barrier" ::: "memory")
#define VMCNT0() asm volatile("s_waitcnt vmcnt(0)" ::: "memory")

// ---------------- convert force f32 -> bf16 (16B stores) ----------------
__global__ __launch_bounds__(256) void cvt_bf16_kernel(
    const float* __restrict__ in, bf16_t* __restrict__ out, int n8)
{
    int i = blockIdx.x * 256 + threadIdx.x;
    if (i >= n8) return;
    float4 f0 = ((const float4*)in)[2 * i];
    float4 f1 = ((const float4*)in)[2 * i + 1];
    bf16x8 o;
    o[0] = (bf16_t)f0.x; o[1] = (bf16_t)f0.y; o[2] = (bf16_t)f0.z; o[3] = (bf16_t)f0.w;
    o[4] = (bf16_t)f1.x; o[5] = (bf16_t)f1.y; o[6] = (bf16_t)f1.z; o[7] = (bf16_t)f1.w;
    ((bf16x8*)out)[i] = o;
}

// ------- transpose W[k][j] -> Wt[j][k] with f32->bf16; z picks matrix -------
__global__ __launch_bounds__(256) void transpose_w_kernel(
    const float* __restrict__ W0, const float* __restrict__ W1,
    const float* __restrict__ W2, bf16_t* __restrict__ Wt)
{
    __shared__ float tile[32][33];
    const float* W = (blockIdx.z == 0) ? W0 : (blockIdx.z == 1) ? W1 : W2;
    bf16_t* dst = Wt + (size_t)blockIdx.z * D_DIM * D_DIM;
    int j0 = blockIdx.x * 32, k0 = blockIdx.y * 32;
    int tx = threadIdx.x, ty = threadIdx.y;      // block (32, 8)
#pragma unroll
    for (int i = 0; i < 4; i++) {
        int k = k0 + ty + i * 8;
        tile[ty + i * 8][tx] = W[(size_t)k * D_DIM + j0 + tx];
    }
    __syncthreads();
#pragma unroll
    for (int i = 0; i < 4; i++) {
        int j = j0 + ty + i * 8;
        dst[(size_t)j * D_DIM + k0 + tx] = (bf16_t)tile[tx][ty + i * 8];
    }
}

// ---------------- fused bf16 GEMM: [8192 x 2048] @ [2048 x 6144] ----------------
// R12 configuration — session best (gemm ~319us / 650 TF, total 407.7us).
// 128^2 tile, BK=64, 8 waves (2m x 4n, wave owns 64x32), 2-phase double-
// buffer, one vmcnt(0)+barrier per K-tile. 16x16x32 MFMA.
// Verified 0-conflict swizzle pair (R7/R8/R12):
//   stage: LDS dest linear, global col slot ^= (row&7)
//   read : slot = (ks*4 + (lane>>4)) ^ (frow&7)
// Ledger (do not revisit): structure changes 0-for-6 — R2 ks-split 8-phase,
// R3 4-ring, R9/R10 3-ring counted-vmcnt, R11 A-in-reg, R14 256^2 8-phase
// (VGPR 96 spill, 18.5GB). Parameter changes 4-for-4: BK64, 2-phase, 8-wave,
// swizzle. R5: bf16 epilogue stores -> acc spill (keep f32). R9: 32x32 MFMA
// frag reads conflict 2.5e7 (keep 16x16). 2-phase stage+drain wall (m233)
// is the binding constraint at ~650 TF.
#define STAGE(LA, LB, T) {                                                     \
    const size_t kofs_ = (size_t)(T) * 64;                                     \
    _Pragma("unroll") for (int j = 0; j < 2; j++) {                            \
        gl_lds16(gA[j] + kofs_, (LA) + j * 4096 + w * 512);                    \
        gl_lds16(gB[j] + kofs_, (LB) + j * 4096 + w * 512);                    \
    } }

#define COMPUTE(LA, LB) {                                                      \
    bf16x8 af[4], bfr[2];                                                      \
    _Pragma("unroll") for (int m = 0; m < 4; m++)                              \
        af[m] = *(const bf16x8*)&(LA)[(wr + m * 16) * 64 + lof0];              \
    _Pragma("unroll") for (int n = 0; n < 2; n++)                              \
        bfr[n] = *(const bf16x8*)&(LB)[(wc + n * 16) * 64 + lof0];             \
    __builtin_amdgcn_s_setprio(1);                                             \
    _Pragma("unroll") for (int m = 0; m < 4; m++)                              \
        _Pragma("unroll") for (int n = 0; n < 2; n++)                          \
            acc[m][n] = __builtin_amdgcn_mfma_f32_16x16x32_bf16(               \
                af[m], bfr[n], acc[m][n], 0, 0, 0);                            \
    __builtin_amdgcn_s_setprio(0);                                             \
    _Pragma("unroll") for (int m = 0; m < 4; m++)                              \
        af[m] = *(const bf16x8*)&(LA)[(wr + m * 16) * 64 + lof1];              \
    _Pragma("unroll") for (int n = 0; n < 2; n++)                              \
        bfr[n] = *(const bf16x8*)&(LB)[(wc + n * 16) * 64 + lof1];             \
    __builtin_amdgcn_s_setprio(1);                                             \
    _Pragma("unroll") for (int m = 0; m < 4; m++)                              \
        _Pragma("unroll") for (int n = 0; n < 2; n++)                          \
            acc[m][n] = __builtin_amdgcn_mfma_f32_16x16x32_bf16(               \
                af[m], bfr[n], acc[m][n], 0, 0, 0);                            \
    __builtin_amdgcn_s_setprio(0);                                             \
}

__global__ __launch_bounds__(512) void gemm_fused_kernel(
    const bf16_t* __restrict__ Abf,   // force bf16 [8192][2048]
    const bf16_t* __restrict__ Wt,    // [6144][2048] (W^T, concat A|dt|B)
    const float* __restrict__ bA, const float* __restrict__ bdt,
    const float* __restrict__ bB, const float* __restrict__ scales,
    float* __restrict__ outA,         // -> d_out x-region (staging)
    float* __restrict__ outDT,        // -> ws
    float* __restrict__ outB)         // -> d_out v-region (staging)
{
    __shared__ bf16_t lds_a0[128 * 64];   // 16 KB
    __shared__ bf16_t lds_a1[128 * 64];
    __shared__ bf16_t lds_b0[128 * 64];
    __shared__ bf16_t lds_b1[128 * 64];   // total 64 KB

    const int bm0 = blockIdx.x * 128;         // M block (fastest)
    const int bn0 = blockIdx.y * 128;         // NT block
    const int t = threadIdx.x;                // 0..511
    const int lane = t & 63, w = t >> 6;      // 8 waves
    const int wr = (w >> 2) * 64;             // 2 m-groups
    const int wc = (w & 3) * 32;              // 4 n-groups

    f32x4 acc[4][2] = {};

    // staging: issue j covers rows j*64 + (t>>3); linear 16B slot t&7,
    // global col pre-swizzled slot ^ (row&7) = (t&7) ^ ((t>>3)&7).
    const int srow = t >> 3;                  // 0..63
    const int scol = (((t & 7) ^ ((t >> 3) & 7)) << 3);   // elements
    const bf16_t* gA[2];
    const bf16_t* gB[2];
#pragma unroll
    for (int j = 0; j < 2; j++) {
        gA[j] = Abf + (size_t)(bm0 + j * 64 + srow) * D_DIM + scol;
        gB[j] = Wt + (size_t)(bn0 + j * 64 + srow) * D_DIM + scol;
    }

    // frag reads (verified 0-conflict): row = frow in 16-row group
    const int frow = lane & 15;
    const int q = lane >> 4;
    const int fx7 = frow & 7;
    const int lof0 = frow * 64 + (((q) ^ fx7) << 3);          // ks=0, elems
    const int lof1 = frow * 64 + (((4 + q) ^ fx7) << 3);      // ks=1, elems

    // prologue: tile 0 into buf0
    STAGE(lds_a0, lds_b0, 0);
    VMCNT0();
    BAR();

    // main loop: 15 iters x 2 K-tiles (computes tiles 0..29), static ping-pong
#pragma unroll 1
    for (int i = 0; i < 15; ++i) {
        const int tt = 2 * i;
        STAGE(lds_a1, lds_b1, tt + 1);
        COMPUTE(lds_a0, lds_b0);
        VMCNT0();
        BAR();
        STAGE(lds_a0, lds_b0, tt + 2);
        COMPUTE(lds_a1, lds_b1);
        VMCNT0();
        BAR();
    }
    // tail: tile 30 in buf0; stage 31 -> buf1; compute 30; compute 31
    STAGE(lds_a1, lds_b1, 31);
    COMPUTE(lds_a0, lds_b0);
    VMCNT0();
    BAR();
    COMPUTE(lds_a1, lds_b1);

    // epilogue: C/D layout col = lane&15, row = (lane>>4)*4 + reg  [m89-verified]
    const int seg = bn0 >> 11;                        // 0=A, 1=dt, 2=rawB
    const int dbase = (bn0 & 2047) + wc + (lane & 15);
    const int rowbase = bm0 + wr + (q << 2);

    if (seg == 0) {
        float bias[2];
#pragma unroll
        for (int n = 0; n < 2; n++) bias[n] = bA[dbase + n * 16];
#pragma unroll
        for (int m = 0; m < 4; m++)
#pragma unroll
            for (int n = 0; n < 2; n++)
#pragma unroll
                for (int r = 0; r < 4; r++) {
                    size_t idx = (size_t)(rowbase + m * 16 + r) * D_DIM + dbase + n * 16;
                    outA[idx] = 1.0f / (1.0f + __expf(-(acc[m][n][r] + bias[n])));
                }
    } else if (seg == 1) {
        float bias[2], sc[2];
#pragma unroll
        for (int n = 0; n < 2; n++) { bias[n] = bdt[dbase + n * 16]; sc[n] = scales[dbase + n * 16]; }
#pragma unroll
        for (int m = 0; m < 4; m++)
#pragma unroll
            for (int n = 0; n < 2; n++)
#pragma unroll
                for (int r = 0; r < 4; r++) {
                    size_t idx = (size_t)(rowbase + m * 16 + r) * D_DIM + dbase + n * 16;
                    float xx = acc[m][n][r] + bias[n];
                    float sp = xx > 0.f ? xx + log1pf(__expf(-xx)) : log1pf(__expf(xx));
                    outDT[idx] = sp * 0.1f * sc[n];
                }
    } else {
        float bias[2];
#pragma unroll
        for (int n = 0; n < 2; n++) bias[n] = bB[dbase + n * 16];
#pragma unroll
        for (int m = 0; m < 4; m++)
#pragma unroll
            for (int n = 0; n < 2; n++)
#pragma unroll
                for (int r = 0; r < 4; r++) {
                    size_t idx = (size_t)(rowbase + m * 16 + r) * D_DIM + dbase + n * 16;
                    outB[idx] = acc[m][n][r] + bias[n];
                }
    }
}

// ---------------- scan pass 1: per-chunk affine aggregates ----------------
// step map: v' = a v + bv ; x' = x + dt v'  =>  (P,R,U,W):
//   v_out = P v + U ; x_out = R v + x + W
// 2 adjacent d-channels per thread (float2 loads).
__global__ __launch_bounds__(256) void scan_pass1_kernel(
    const float* __restrict__ Aarr, const float* __restrict__ Braw,
    const float* __restrict__ dtv, float4* __restrict__ agg)
{
    int pp = blockIdx.x * 256 + threadIdx.x;    // 65536 pair-threads
    int dp = (pp & 1023) << 1;                  // d pair base
    int c = (pp >> 10) & (NCH - 1);
    int b = pp >> 14;
    size_t base = ((size_t)(b * L_SEQ + c * CHUNK)) * D_DIM + dp;
    float P0 = 1.f, R0 = 0.f, U0 = 0.f, W0 = 0.f;
    float P1 = 1.f, R1 = 0.f, U1 = 0.f, W1 = 0.f;
#pragma unroll 4
    for (int tt = 0; tt < CHUNK; tt++) {
        size_t idx = base + (size_t)tt * D_DIM;
        float2 a2  = *(const float2*)&Aarr[idx];
        float2 rb2 = *(const float2*)&Braw[idx];
        float2 dt2 = *(const float2*)&dtv[idx];
        float bv0 = rb2.x * dt2.x, bv1 = rb2.y * dt2.y;
        float da0 = dt2.x * a2.x,  da1 = dt2.y * a2.y;
        R0 = da0 * P0 + R0;  W0 = da0 * U0 + dt2.x * bv0 + W0;
        U0 = a2.x * U0 + bv0;  P0 = a2.x * P0;
        R1 = da1 * P1 + R1;  W1 = da1 * U1 + dt2.y * bv1 + W1;
        U1 = a2.y * U1 + bv1;  P1 = a2.y * P1;
    }
    int ch = ((b * NCH + c) << 11) + dp;
    agg[ch]     = make_float4(P0, R0, U0, W0);
    agg[ch + 1] = make_float4(P1, R1, U1, W1);
}

// ---------------- scan pass 2: combine chunk aggregates ----------------
__global__ __launch_bounds__(256) void scan_pass2_kernel(
    const float4* __restrict__ agg, float2* __restrict__ pre)
{
    int tid = blockIdx.x * 256 + threadIdx.x;   // 8192 channels
    int d = tid & (D_DIM - 1);
    int b = tid >> 11;
    float v = 0.f, x = 0.f;
#pragma unroll
    for (int c = 0; c < NCH; c++) {
        int i = ((b * NCH + c) << 11) + d;
        float4 g = agg[i];
        pre[i] = make_float2(v, x);             // state entering chunk c
        float vn = g.x * v + g.z;
        x = g.y * v + x + g.w;                  // uses old v
        v = vn;
    }
}

// ---------------- scan pass 3: replay chunk, write outputs in place ----------------
// A staged in xout, rawB staged in vout; overwritten in place
// (read-before-write, same element, same thread).
__global__ __launch_bounds__(256) void scan_pass3_kernel(
    const float* __restrict__ dtv, const float2* __restrict__ pre,
    float* __restrict__ xout, float* __restrict__ vout)
{
    int pp = blockIdx.x * 256 + threadIdx.x;    // 65536 pair-threads
    int dp = (pp & 1023) << 1;
    int c = (pp >> 10) & (NCH - 1);
    int b = pp >> 14;
    int ch = ((b * NCH + c) << 11) + dp;
    float4 pv = *(const float4*)&pre[ch];       // {v0,x0,v1,x1}
    float v0 = pv.x, x0 = pv.y, v1 = pv.z, x1 = pv.w;
    size_t base = ((size_t)(b * L_SEQ + c * CHUNK)) * D_DIM + dp;
#pragma unroll 4
    for (int tt = 0; tt < CHUNK; tt++) {
        size_t idx = base + (size_t)tt * D_DIM;
        float2 a2  = *(const float2*)&xout[idx];   // A (staged)
        float2 rb2 = *(const float2*)&vout[idx];   // rawB (staged)
        float2 dt2 = *(const float2*)&dtv[idx];
        v0 = a2.x * v0 + rb2.x * dt2.x;
        x0 = x0 + v0 * dt2.x;
        v1 = a2.y * v1 + rb2.y * dt2.y;
        x1 = x1 + v1 * dt2.y;
        *(float2*)&vout[idx] = make_float2(v0, v1);
        *(float2*)&xout[idx] = make_float2(x0, x1);
    }
}

extern "C" void kernel_launch(void* const* d_in, const int* in_sizes, int n_in,
                              void* d_out, int out_size, void* d_ws, size_t ws_size,
                              hipStream_t stream) {
    // inputs: 0:x 1:v 2:force 3:WA 4:bA 5:WB 6:bB 7:Wdt 8:bdt 9:scales
    const float* force  = (const float*)d_in[2];
    const float* WA     = (const float*)d_in[3];
    const float* bA     = (const float*)d_in[4];
    const float* WB     = (const float*)d_in[5];
    const float* bB     = (const float*)d_in[6];
    const float* Wdt    = (const float*)d_in[7];
    const float* bdt    = (const float*)d_in[8];
    const float* scales = (const float*)d_in[9];

    float* xout = (float*)d_out;                          // x_seq [8192*2048]
    float* vout = xout + (size_t)M_ROWS * D_DIM;          // v_seq

    // ws layout (123 MiB): R1 layout
    char* ws = (char*)d_ws;
    bf16_t* fbf = (bf16_t*)ws;                                     // 32 MB
    bf16_t* wt  = (bf16_t*)(ws + (size_t)33554432);                // 24 MB
    float*  dtv = (float*)(ws + (size_t)33554432 + 25165824);      // 64 MB
    float4* agg = (float4*)(ws + (size_t)33554432 + 25165824 + 67108864); // 2 MB
    float2* pre = (float2*)(ws + (size_t)33554432 + 25165824 + 67108864 + 2097152); // 1 MB

    // 1) force -> bf16
    {
        int n8 = M_ROWS * D_DIM / 8;
        cvt_bf16_kernel<<<n8 / 256, 256, 0, stream>>>(force, fbf, n8);
    }
    // 2) transpose + convert weights into concat [6144][2048]: A | dt | B
    {
        dim3 grid(D_DIM / 32, D_DIM / 32, 3), block(32, 8);
        transpose_w_kernel<<<grid, block, 0, stream>>>(WA, Wdt, WB, wt);
    }
    // 3) fused GEMM + activations (BK=64, 2-phase dbuf, 8 waves / 128^2)
    {
        dim3 grid(M_ROWS / 128, NT_COLS / 128);   // (64, 48)
        gemm_fused_kernel<<<grid, 512, 0, stream>>>(fbf, wt, bA, bdt, bB, scales,
                                                    xout, dtv, vout);
    }
    // 4-6) chunked associative scan (2 channels per thread)
    scan_pass1_kernel<<<(B_SZ * NCH * D_DIM / 2) / 256, 256, 0, stream>>>(xout, vout, dtv, agg);
    scan_pass2_kernel<<<(B_SZ * D_DIM) / 256, 256, 0, stream>>>(agg, pre);
    scan_pass3_kernel<<<(B_SZ * NCH * D_DIM / 2) / 256, 256, 0, stream>>>(dtv, pre, xout, vout);
}